// Round 9
// baseline (243.925 us; speedup 1.0000x reference)
//
#include <hip/hip_runtime.h>
#include <hip/hip_bf16.h>
#include <stdint.h>

#define B_ 4
#define S_ 2048
#define E_ 1024
#define H_ 16
#define D_ 64
#define M_ 8192     // B*S
#define N1_ 3072    // 3*E
#define QSCALE 0.18033688011112042f   // 0.125 * log2(e)

typedef __attribute__((ext_vector_type(8))) short bf16x8;
typedef __attribute__((ext_vector_type(4))) float f32x4;
typedef __attribute__((ext_vector_type(16))) float f32x16;
typedef __attribute__((ext_vector_type(4))) short short4v;

__device__ __forceinline__ short f2b(float f) {
  union { float f; unsigned u; } c; c.f = f;
  unsigned u = c.u + 0x7fffu + ((c.u >> 16) & 1u);
  return (short)(u >> 16);
}

__device__ __forceinline__ float fexp2(float x) {
#if __has_builtin(__builtin_amdgcn_exp2f)
  return __builtin_amdgcn_exp2f(x);
#else
  return exp2f(x);
#endif
}

__device__ __forceinline__ unsigned cvtpk(float lo, float hi2) {
  unsigned r;
  asm("v_cvt_pk_bf16_f32 %0, %1, %2" : "=v"(r) : "v"(lo), "v"(hi2));
  return r;
}

__device__ __forceinline__ void gload16(const void* g, void* l) {
  __builtin_amdgcn_global_load_lds((const __attribute__((address_space(1))) void*)g,
                                   (__attribute__((address_space(3))) void*)l, 16, 0, 0);
}

// ---- x (f32) -> bf16, 8 elems/thread ----
__global__ void conv_kernel(const float* __restrict__ in, short* __restrict__ out) {
  int idx = blockIdx.x * 256 + threadIdx.x;
  const float4* p = (const float4*)in;
  float4 a = p[(size_t)idx * 2];
  float4 b = p[(size_t)idx * 2 + 1];
  bf16x8 v;
  v[0] = f2b(a.x); v[1] = f2b(a.y); v[2] = f2b(a.z); v[3] = f2b(a.w);
  v[4] = f2b(b.x); v[5] = f2b(b.y); v[6] = f2b(b.z); v[7] = f2b(b.w);
  *(bf16x8*)(out + (size_t)idx * 8) = v;
}

// ---- in [K][N] f32 -> out [N][K] bf16 (tiled transpose) ----
__global__ void trans_kernel(const float* __restrict__ in, short* __restrict__ out,
                             int K, int N) {
  __shared__ float tile[32][33];
  int n0 = blockIdx.x * 32, k0 = blockIdx.y * 32;
  int tx = threadIdx.x & 31, ty = threadIdx.x >> 5;
  #pragma unroll
  for (int i = 0; i < 4; ++i)
    tile[ty + i * 8][tx] = in[(size_t)(k0 + ty + i * 8) * N + n0 + tx];
  __syncthreads();
  #pragma unroll
  for (int i = 0; i < 4; ++i)
    out[(size_t)(n0 + ty + i * 8) * K + k0 + tx] = f2b(tile[tx][ty + i * 8]);
}

// ---- C[M][N] = A[M][K] * Bt[N][K]^T + bias ; bf16 MFMA, 128x128 tile, BK=64
//      (round-4 m97 structure: 32 KB LDS, multi-block implicit overlap) ----
template<bool SCATTER>
__global__ __launch_bounds__(256)
void gemm_kernel(const short* __restrict__ A, const short* __restrict__ Bt,
                 const float* __restrict__ bias,
                 short* __restrict__ oQ, short* __restrict__ oK, short* __restrict__ oV,
                 float* __restrict__ oC, int Kdim, int Ndim)
{
  __shared__ short Asub[128 * 64];
  __shared__ short Bsub[128 * 64];
  const int tid = threadIdx.x;
  const int l = tid & 63, w = tid >> 6;
  const int wr = w >> 1, wc = w & 1;
  const int lr = l & 15, lg = l >> 4;

  // T1: bijective XCD swizzle (nwg % 8 == 0 for both launches)
  const int nwg = gridDim.x * gridDim.y;
  const int lin = blockIdx.y * gridDim.x + blockIdx.x;
  const int lin2 = (lin & 7) * (nwg >> 3) + (lin >> 3);
  const int m0 = (lin2 / gridDim.x) * 128, n0 = (lin2 % gridDim.x) * 128;

  const int srow = w * 8 + (l >> 3);
  const int scol = ((l & 7) ^ (l >> 3)) << 3;   // pre-swizzled source col (elems)

  f32x4 acc[4][4] = {};

  for (int k0 = 0; k0 < Kdim; k0 += 64) {
    __syncthreads();
    #pragma unroll
    for (int i = 0; i < 4; ++i) {
      gload16(A  + (size_t)(m0 + i * 32 + srow) * Kdim + k0 + scol,
              (char*)Asub + (i * 32 + w * 8) * 128);
      gload16(Bt + (size_t)(n0 + i * 32 + srow) * Kdim + k0 + scol,
              (char*)Bsub + (i * 32 + w * 8) * 128);
    }
    __syncthreads();
    #pragma unroll
    for (int kk = 0; kk < 64; kk += 32) {
      bf16x8 af[4], bfr[4];
      const int ce2 = (kk + lg * 8) << 1;
      #pragma unroll
      for (int mi = 0; mi < 4; ++mi) {
        int rr = wr * 64 + mi * 16 + lr;
        af[mi] = *(const bf16x8*)((const char*)Asub + rr * 128 + (ce2 ^ ((rr & 7) << 4)));
      }
      #pragma unroll
      for (int ni = 0; ni < 4; ++ni) {
        int rr = wc * 64 + ni * 16 + lr;
        bfr[ni] = *(const bf16x8*)((const char*)Bsub + rr * 128 + (ce2 ^ ((rr & 7) << 4)));
      }
      __builtin_amdgcn_s_setprio(1);
      #pragma unroll
      for (int mi = 0; mi < 4; ++mi)
        #pragma unroll
        for (int ni = 0; ni < 4; ++ni)
          acc[mi][ni] = __builtin_amdgcn_mfma_f32_16x16x32_bf16(af[mi], bfr[ni], acc[mi][ni], 0, 0, 0);
      __builtin_amdgcn_s_setprio(0);
    }
  }

  #pragma unroll
  for (int mi = 0; mi < 4; ++mi) {
    #pragma unroll
    for (int ni = 0; ni < 4; ++ni) {
      const int row0 = m0 + wr * 64 + mi * 16 + lg * 4;
      const int col  = n0 + wc * 64 + ni * 16 + lr;
      const float bv = bias[col];
      if constexpr (SCATTER) {
        const int which = col >> 10;
        const int e = col & 1023;
        const int h = e >> 6, d = e & 63;
        const int b = row0 >> 11, s = row0 & 2047;
        if (which == 2) {
          short4v pv;
          #pragma unroll
          for (int r = 0; r < 4; ++r) pv[r] = f2b(acc[mi][ni][r] + bv);
          *(short4v*)(oV + ((size_t)((b * H_ + h) * D_ + d)) * S_ + s) = pv;
        } else {
          short* dst = which ? oK : oQ;
          const float sc = which ? 1.0f : QSCALE;
          #pragma unroll
          for (int r = 0; r < 4; ++r)
            dst[((size_t)((b * H_ + h) * S_ + s + r)) * D_ + d] = f2b((acc[mi][ni][r] + bv) * sc);
        }
      } else {
        #pragma unroll
        for (int r = 0; r < 4; ++r)
          oC[(size_t)(row0 + r) * Ndim + col] = acc[mi][ni][r] + bv;
      }
    }
  }
}

// ---- causal flash attention, REGISTER-direct K/V (no LDS staging, no barriers
//      in the main loop). 8 waves: g = w>>2 takes KV tiles of parity g (each
//      wave fully independent), qw = w&3 picks the 32-row q-subtile.
//      A-fragments are per-lane disjoint: lane (lc,hi) loads K[key=lc(+32)] and
//      vT[d=lc(+32)] slices straight to VGPRs. LDS used only for the merge. ----
__global__ __launch_bounds__(512)
void attn_kernel(const short* __restrict__ Q, const short* __restrict__ K,
                 const short* __restrict__ vT, short* __restrict__ O)
{
  __shared__ float accsA[256 * 17];   // stride-17 f32: 2-way banks = free
  __shared__ float accsB[256 * 17];
  __shared__ float stats[256];

  const int qt = (S_ / 128 - 1) - (blockIdx.x >> 6);   // descending work order
  const int bh = blockIdx.x & 63;
  const int tid = threadIdx.x, l = tid & 63, w = tid >> 6;
  const int qw = w & 3, g = w >> 2;
  const int lc = l & 31, hi = l >> 5;

  const short* Qb = Q  + (size_t)bh * (S_ * D_);
  const short* Kb = K  + (size_t)bh * (S_ * D_);
  const short* Vg = vT + (size_t)bh * (S_ * D_);

  const int q0w = qt * 128 + qw * 32;
  const int ktL = (q0w + 31) >> 6;             // last KV tile this q-subtile needs
  const int nAct = (ktL < g) ? 0 : ((ktL - g) >> 1) + 1;   // active tiles, this wave

  bf16x8 qr[4];
  #pragma unroll
  for (int ds = 0; ds < 4; ++ds)
    qr[ds] = *(const bf16x8*)(Qb + (size_t)(q0w + lc) * D_ + ds * 16 + hi * 8);

  f32x16 accA{}, accB{};          // O^T accum: rows=d (dtile 0/1), col=q=lc
  float lsum = 0.f;

  for (int i = 0; i < nAct; ++i) {
    const int kt = 2 * i + g;
    // ---- K fragments: rows (key) lc and lc+32, direct global->reg ----
    const short* Kr = Kb + (size_t)(kt * 64 + lc) * D_ + hi * 8;
    bf16x8 ka[4], kb2[4];
    #pragma unroll
    for (int ds = 0; ds < 4; ++ds) {
      ka[ds]  = *(const bf16x8*)(Kr + ds * 16);
      kb2[ds] = *(const bf16x8*)(Kr + 32 * D_ + ds * 16);
    }
    // ---- S^T = K * Q^T ----
    f32x16 s0{}, s1{};
    __builtin_amdgcn_s_setprio(1);
    #pragma unroll
    for (int ds = 0; ds < 4; ++ds) {
      s0 = __builtin_amdgcn_mfma_f32_32x32x16_bf16(ka[ds],  qr[ds], s0, 0, 0, 0);
      s1 = __builtin_amdgcn_mfma_f32_32x32x16_bf16(kb2[ds], qr[ds], s1, 0, 0, 0);
    }
    __builtin_amdgcn_s_setprio(0);
    // ---- V fragments: rows (d) lc and lc+32, issued before the VALU block ----
    const short* Vr = Vg + (size_t)lc * S_ + kt * 64 + hi * 8;
    bf16x8 va[4], vb2[4];
    #pragma unroll
    for (int ks = 0; ks < 4; ++ks) {
      va[ks]  = *(const bf16x8*)(Vr + ks * 16);
      vb2[ks] = *(const bf16x8*)(Vr + 32 * S_ + ks * 16);
    }
    float p[32];
    #pragma unroll
    for (int r = 0; r < 16; ++r) { p[r] = s0[r]; p[16 + r] = s1[r]; }
    if (kt == ktL) {                 // diagonal tile: mask key > q
      const int qq = q0w + lc - kt * 64;
      #pragma unroll
      for (int r = 0; r < 16; ++r) {
        const int k0 = (r & 3) + 8 * (r >> 2) + 4 * hi;
        if (k0 > qq)      p[r]      = -1e30f;
        if (k0 + 32 > qq) p[16 + r] = -1e30f;
      }
    }
    // ---- no-max softmax: p = exp2(s) raw (s already in log2 units) ----
    float rs0 = 0.f, rs1 = 0.f, rs2 = 0.f, rs3 = 0.f;
    #pragma unroll
    for (int r = 0; r < 8; ++r) {
      p[r]      = fexp2(p[r]);      rs0 += p[r];
      p[8 + r]  = fexp2(p[8 + r]);  rs1 += p[8 + r];
      p[16 + r] = fexp2(p[16 + r]); rs2 += p[16 + r];
      p[24 + r] = fexp2(p[24 + r]); rs3 += p[24 + r];
    }
    float rs = (rs0 + rs1) + (rs2 + rs3);
    rs += __shfl_xor(rs, 32);
    lsum += rs;
    // ---- O^T += V^T * P^T ----
    #pragma unroll
    for (int ks = 0; ks < 4; ++ks) {
      const int b8 = ks * 8;
      const unsigned A0 = cvtpk(p[b8 + 0], p[b8 + 1]);
      const unsigned A1 = cvtpk(p[b8 + 2], p[b8 + 3]);
      const unsigned B0 = cvtpk(p[b8 + 4], p[b8 + 5]);
      const unsigned B1 = cvtpk(p[b8 + 6], p[b8 + 7]);
      const unsigned u0 = __shfl_xor(hi ? A0 : B0, 32);
      const unsigned u1 = __shfl_xor(hi ? A1 : B1, 32);
      union { unsigned u[4]; bf16x8 v; } W;
      W.u[0] = hi ? u0 : A0;
      W.u[1] = hi ? u1 : A1;
      W.u[2] = hi ? B0 : u0;
      W.u[3] = hi ? B1 : u1;
      __builtin_amdgcn_s_setprio(1);
      accA = __builtin_amdgcn_mfma_f32_32x32x16_bf16(va[ks],  W.v, accA, 0, 0, 0);
      accB = __builtin_amdgcn_mfma_f32_32x32x16_bf16(vb2[ks], W.v, accB, 0, 0, 0);
      __builtin_amdgcn_s_setprio(0);
    }
  }

  // ---- merge the two KV-groups via LDS ----
  const int mi = qw * 64 + l;
  if (g == 1) {
    #pragma unroll
    for (int r = 0; r < 16; ++r) {
      accsA[mi * 17 + r] = accA[r];
      accsB[mi * 17 + r] = accB[r];
    }
    stats[mi] = lsum;
  }
  __syncthreads();
  if (g == 0) {
    const float rl = 1.0f / (lsum + stats[mi]);
    const int h = bh & 15, b = bh >> 4;
    short* Ob = O + ((size_t)(b * S_ + q0w + lc)) * E_ + h * 64;
    #pragma unroll
    for (int gq = 0; gq < 4; ++gq) {
      short4v o0, o1;
      #pragma unroll
      for (int i = 0; i < 4; ++i) {
        o0[i] = f2b((accA[4 * gq + i] + accsA[mi * 17 + 4 * gq + i]) * rl);
        o1[i] = f2b((accB[4 * gq + i] + accsB[mi * 17 + 4 * gq + i]) * rl);
      }
      *(short4v*)(Ob + 8 * gq + 4 * hi) = o0;
      *(short4v*)(Ob + 32 + 8 * gq + 4 * hi) = o1;
    }
  }
}

extern "C" void kernel_launch(void* const* d_in, const int* in_sizes, int n_in,
                              void* d_out, int out_size, void* d_ws, size_t ws_size,
                              hipStream_t stream)
{
  const float* x     = (const float*)d_in[0];
  const float* Wqkv  = (const float*)d_in[1];
  const float* bqkv  = (const float*)d_in[2];
  const float* Wproj = (const float*)d_in[3];
  const float* bproj = (const float*)d_in[4];
  float* out = (float*)d_out;

  char* ws = (char*)d_ws;
  short* xb     = (short*)(ws + (size_t)0);                 // 16 MB  [8192][1024]
  short* wqkvT  = (short*)(ws + (size_t)16 * 1024 * 1024);  //  6 MB  [3072][1024]
  short* wprojT = (short*)(ws + (size_t)22 * 1024 * 1024);  //  2 MB  [1024][1024]
  short* qb     = (short*)(ws + (size_t)24 * 1024 * 1024);  // 16 MB  [B][H][S][D] (scaled)
  short* kb     = (short*)(ws + (size_t)40 * 1024 * 1024);  // 16 MB  [B][H][S][D]
  short* vb     = (short*)(ws + (size_t)56 * 1024 * 1024);  // 16 MB  [B][H][D][S] (transposed)
  short* ob     = (short*)(ws + (size_t)72 * 1024 * 1024);  // 16 MB  [8192][1024]

  conv_kernel<<<4096, 256, 0, stream>>>(x, xb);
  trans_kernel<<<dim3(N1_ / 32, E_ / 32), 256, 0, stream>>>(Wqkv, wqkvT, E_, N1_);
  trans_kernel<<<dim3(E_ / 32, E_ / 32), 256, 0, stream>>>(Wproj, wprojT, E_, E_);
  gemm_kernel<true><<<dim3(N1_ / 128, M_ / 128), 256, 0, stream>>>(
      xb, wqkvT, bqkv, qb, kb, vb, nullptr, E_, N1_);
  attn_kernel<<<(S_ / 128) * (B_ * H_), 512, 0, stream>>>(qb, kb, vb, ob);
  gemm_kernel<false><<<dim3(E_ / 128, M_ / 128), 256, 0, stream>>>(
      ob, wprojT, bproj, nullptr, nullptr, nullptr, out, E_, E_);
}

// Round 10
// 164.199 us; speedup vs baseline: 1.4855x; 1.4855x over previous
//
#include <hip/hip_runtime.h>
#include <hip/hip_bf16.h>
#include <stdint.h>

#define B_ 4
#define S_ 2048
#define E_ 1024
#define H_ 16
#define D_ 64
#define M_ 8192     // B*S
#define N1_ 3072    // 3*E
#define QSCALE 0.18033688011112042f   // 0.125 * log2(e)

typedef __attribute__((ext_vector_type(8))) short bf16x8;
typedef __attribute__((ext_vector_type(4))) float f32x4;
typedef __attribute__((ext_vector_type(16))) float f32x16;
typedef __attribute__((ext_vector_type(4))) short short4v;

__device__ __forceinline__ short f2b(float f) {
  union { float f; unsigned u; } c; c.f = f;
  unsigned u = c.u + 0x7fffu + ((c.u >> 16) & 1u);
  return (short)(u >> 16);
}

__device__ __forceinline__ float fexp2(float x) {
#if __has_builtin(__builtin_amdgcn_exp2f)
  return __builtin_amdgcn_exp2f(x);
#else
  return exp2f(x);
#endif
}

__device__ __forceinline__ unsigned cvtpk(float lo, float hi2) {
  unsigned r;
  asm("v_cvt_pk_bf16_f32 %0, %1, %2" : "=v"(r) : "v"(lo), "v"(hi2));
  return r;
}

__device__ __forceinline__ void gload16(const void* g, void* l) {
  __builtin_amdgcn_global_load_lds((const __attribute__((address_space(1))) void*)g,
                                   (__attribute__((address_space(3))) void*)l, 16, 0, 0);
}

// ---- x (f32) -> bf16, 8 elems/thread ----
__global__ void conv_kernel(const float* __restrict__ in, short* __restrict__ out) {
  int idx = blockIdx.x * 256 + threadIdx.x;
  const float4* p = (const float4*)in;
  float4 a = p[(size_t)idx * 2];
  float4 b = p[(size_t)idx * 2 + 1];
  bf16x8 v;
  v[0] = f2b(a.x); v[1] = f2b(a.y); v[2] = f2b(a.z); v[3] = f2b(a.w);
  v[4] = f2b(b.x); v[5] = f2b(b.y); v[6] = f2b(b.z); v[7] = f2b(b.w);
  *(bf16x8*)(out + (size_t)idx * 8) = v;
}

// ---- in [K][N] f32 -> out [N][K] bf16 (tiled transpose) ----
__global__ void trans_kernel(const float* __restrict__ in, short* __restrict__ out,
                             int K, int N) {
  __shared__ float tile[32][33];
  int n0 = blockIdx.x * 32, k0 = blockIdx.y * 32;
  int tx = threadIdx.x & 31, ty = threadIdx.x >> 5;
  #pragma unroll
  for (int i = 0; i < 4; ++i)
    tile[ty + i * 8][tx] = in[(size_t)(k0 + ty + i * 8) * N + n0 + tx];
  __syncthreads();
  #pragma unroll
  for (int i = 0; i < 4; ++i)
    out[(size_t)(n0 + ty + i * 8) * K + k0 + tx] = f2b(tile[tx][ty + i * 8]);
}

// ---- C[M][N] = A[M][K] * Bt[N][K]^T + bias ; bf16 MFMA, 128x128 tile, BK=64
//      (round-4 m97 structure: 32 KB LDS, multi-block implicit overlap) ----
template<bool SCATTER>
__global__ __launch_bounds__(256)
void gemm_kernel(const short* __restrict__ A, const short* __restrict__ Bt,
                 const float* __restrict__ bias,
                 short* __restrict__ oQ, short* __restrict__ oK, short* __restrict__ oV,
                 float* __restrict__ oC, int Kdim, int Ndim)
{
  __shared__ short Asub[128 * 64];
  __shared__ short Bsub[128 * 64];
  const int tid = threadIdx.x;
  const int l = tid & 63, w = tid >> 6;
  const int wr = w >> 1, wc = w & 1;
  const int lr = l & 15, lg = l >> 4;

  // T1: bijective XCD swizzle (nwg % 8 == 0 for both launches)
  const int nwg = gridDim.x * gridDim.y;
  const int lin = blockIdx.y * gridDim.x + blockIdx.x;
  const int lin2 = (lin & 7) * (nwg >> 3) + (lin >> 3);
  const int m0 = (lin2 / gridDim.x) * 128, n0 = (lin2 % gridDim.x) * 128;

  const int srow = w * 8 + (l >> 3);
  const int scol = ((l & 7) ^ (l >> 3)) << 3;   // pre-swizzled source col (elems)

  f32x4 acc[4][4] = {};

  for (int k0 = 0; k0 < Kdim; k0 += 64) {
    __syncthreads();
    #pragma unroll
    for (int i = 0; i < 4; ++i) {
      gload16(A  + (size_t)(m0 + i * 32 + srow) * Kdim + k0 + scol,
              (char*)Asub + (i * 32 + w * 8) * 128);
      gload16(Bt + (size_t)(n0 + i * 32 + srow) * Kdim + k0 + scol,
              (char*)Bsub + (i * 32 + w * 8) * 128);
    }
    __syncthreads();
    #pragma unroll
    for (int kk = 0; kk < 64; kk += 32) {
      bf16x8 af[4], bfr[4];
      const int ce2 = (kk + lg * 8) << 1;
      #pragma unroll
      for (int mi = 0; mi < 4; ++mi) {
        int rr = wr * 64 + mi * 16 + lr;
        af[mi] = *(const bf16x8*)((const char*)Asub + rr * 128 + (ce2 ^ ((rr & 7) << 4)));
      }
      #pragma unroll
      for (int ni = 0; ni < 4; ++ni) {
        int rr = wc * 64 + ni * 16 + lr;
        bfr[ni] = *(const bf16x8*)((const char*)Bsub + rr * 128 + (ce2 ^ ((rr & 7) << 4)));
      }
      __builtin_amdgcn_s_setprio(1);
      #pragma unroll
      for (int mi = 0; mi < 4; ++mi)
        #pragma unroll
        for (int ni = 0; ni < 4; ++ni)
          acc[mi][ni] = __builtin_amdgcn_mfma_f32_16x16x32_bf16(af[mi], bfr[ni], acc[mi][ni], 0, 0, 0);
      __builtin_amdgcn_s_setprio(0);
    }
  }

  #pragma unroll
  for (int mi = 0; mi < 4; ++mi) {
    #pragma unroll
    for (int ni = 0; ni < 4; ++ni) {
      const int row0 = m0 + wr * 64 + mi * 16 + lg * 4;
      const int col  = n0 + wc * 64 + ni * 16 + lr;
      const float bv = bias[col];
      if constexpr (SCATTER) {
        const int which = col >> 10;
        const int e = col & 1023;
        const int h = e >> 6, d = e & 63;
        const int b = row0 >> 11, s = row0 & 2047;
        if (which == 2) {
          short4v pv;
          #pragma unroll
          for (int r = 0; r < 4; ++r) pv[r] = f2b(acc[mi][ni][r] + bv);
          *(short4v*)(oV + ((size_t)((b * H_ + h) * D_ + d)) * S_ + s) = pv;
        } else {
          short* dst = which ? oK : oQ;
          const float sc = which ? 1.0f : QSCALE;
          #pragma unroll
          for (int r = 0; r < 4; ++r)
            dst[((size_t)((b * H_ + h) * S_ + s + r)) * D_ + d] = f2b((acc[mi][ni][r] + bv) * sc);
        }
      } else {
        #pragma unroll
        for (int r = 0; r < 4; ++r)
          oC[(size_t)(row0 + r) * Ndim + col] = acc[mi][ni][r] + bv;
      }
    }
  }
}

// ---- causal flash attention: 4 waves x 32 q-rows, NO KV split, 32 KB LDS
//      (4 blocks/CU), double-buffered K/V via global_load_lds, no-max softmax,
//      descending-qt launch order. No merge phase. ----
__global__ __launch_bounds__(256, 4)
void attn_kernel(const short* __restrict__ Q, const short* __restrict__ K,
                 const short* __restrict__ vT, short* __restrict__ O)
{
  __shared__ short Kl[2][64 * 64];   // [par][key][d], rows XOR-swizzled
  __shared__ short Vl[2][64 * 64];   // [par][d][key], rows XOR-swizzled

  const int qt = (S_ / 128 - 1) - (blockIdx.x >> 6);   // descending work order
  const int bh = blockIdx.x & 63;
  const int tid = threadIdx.x, l = tid & 63, w = tid >> 6;   // w = q-subtile 0..3
  const int lc = l & 31, hi = l >> 5;
  const int sl8 = l >> 3;
  const int scol = 8 * ((l & 7) ^ sl8);          // pre-swizzled source col (elems)

  const short* Qb = Q  + (size_t)bh * (S_ * D_);
  const short* Kb = K  + (size_t)bh * (S_ * D_);
  const short* Vg = vT + (size_t)bh * (S_ * D_);

  const int q0w = qt * 128 + w * 32;
  const int ktL = (q0w + 31) >> 6;       // last KV tile this q-subtile needs
  const int NTB = 2 * qt + 2;            // tiles the block stages

  bf16x8 qr[4];
  #pragma unroll
  for (int ds = 0; ds < 4; ++ds)
    qr[ds] = *(const bf16x8*)(Qb + (size_t)(q0w + lc) * D_ + ds * 16 + hi * 8);

  f32x16 accA{}, accB{};          // O^T accum: rows=d (dtile 0/1), col=q=lc
  float lsum = 0.f;
  const int rsw = (lc & 7) << 4;

  // each wave stages 16 K-rows and 16 V-rows per tile (2 gload16 each)
  auto stage = [&](int buf, int kt2) {
    short* kl = &Kl[buf][(w * 16) * 64];
    short* vl = &Vl[buf][(w * 16) * 64];
    const size_t kr = (size_t)(kt2 * 64 + w * 16 + sl8);
    gload16(Kb + kr * 64 + scol, kl);
    gload16(Kb + (kr + 8) * 64 + scol, kl + 8 * 64);
    const size_t vr = (size_t)(w * 16 + sl8);
    gload16(Vg + vr * S_ + kt2 * 64 + scol, vl);
    gload16(Vg + (vr + 8) * S_ + kt2 * 64 + scol, vl + 8 * 64);
  };

  stage(0, 0);
  __syncthreads();

  for (int kt = 0; kt < NTB; ++kt) {
    const int cur = kt & 1;
    if (kt + 1 < NTB) stage(cur ^ 1, kt + 1);

    if (kt <= ktL) {
      const char* Kc = (const char*)Kl[cur];
      const char* Vc = (const char*)Vl[cur];
      // ---- S^T = K * Q^T ----
      f32x16 s0{}, s1{};
      __builtin_amdgcn_s_setprio(1);
      #pragma unroll
      for (int ds = 0; ds < 4; ++ds) {
        const int byt = ds * 32 + hi * 16;
        bf16x8 a0 = *(const bf16x8*)(Kc + lc * 128 + (byt ^ rsw));
        bf16x8 a1 = *(const bf16x8*)(Kc + (32 + lc) * 128 + (byt ^ rsw));
        s0 = __builtin_amdgcn_mfma_f32_32x32x16_bf16(a0, qr[ds], s0, 0, 0, 0);
        s1 = __builtin_amdgcn_mfma_f32_32x32x16_bf16(a1, qr[ds], s1, 0, 0, 0);
      }
      __builtin_amdgcn_s_setprio(0);
      float p[32];
      #pragma unroll
      for (int r = 0; r < 16; ++r) { p[r] = s0[r]; p[16 + r] = s1[r]; }
      if (kt == ktL) {           // diagonal tile: mask key > q
        const int qq = q0w + lc - kt * 64;
        #pragma unroll
        for (int r = 0; r < 16; ++r) {
          const int k0 = (r & 3) + 8 * (r >> 2) + 4 * hi;
          if (k0 > qq)      p[r]      = -1e30f;
          if (k0 + 32 > qq) p[16 + r] = -1e30f;
        }
      }
      // ---- no-max softmax: p = exp2(s) raw (s already in log2 units) ----
      float rs0 = 0.f, rs1 = 0.f, rs2 = 0.f, rs3 = 0.f;
      #pragma unroll
      for (int r = 0; r < 8; ++r) {
        p[r]      = fexp2(p[r]);      rs0 += p[r];
        p[8 + r]  = fexp2(p[8 + r]);  rs1 += p[8 + r];
        p[16 + r] = fexp2(p[16 + r]); rs2 += p[16 + r];
        p[24 + r] = fexp2(p[24 + r]); rs3 += p[24 + r];
      }
      float rs = (rs0 + rs1) + (rs2 + rs3);
      rs += __shfl_xor(rs, 32);
      lsum += rs;
      // ---- O^T += V^T * P^T ----
      #pragma unroll
      for (int ks = 0; ks < 4; ++ks) {
        const int b8 = ks * 8;
        const unsigned A0 = cvtpk(p[b8 + 0], p[b8 + 1]);
        const unsigned A1 = cvtpk(p[b8 + 2], p[b8 + 3]);
        const unsigned B0 = cvtpk(p[b8 + 4], p[b8 + 5]);
        const unsigned B1 = cvtpk(p[b8 + 6], p[b8 + 7]);
        const unsigned u0 = __shfl_xor(hi ? A0 : B0, 32);
        const unsigned u1 = __shfl_xor(hi ? A1 : B1, 32);
        union { unsigned u[4]; bf16x8 v; } W;
        W.u[0] = hi ? u0 : A0;
        W.u[1] = hi ? u1 : A1;
        W.u[2] = hi ? B0 : u0;
        W.u[3] = hi ? B1 : u1;
        const int byt = ks * 32 + hi * 16;
        bf16x8 va = *(const bf16x8*)(Vc + lc * 128 + (byt ^ rsw));
        bf16x8 vb = *(const bf16x8*)(Vc + (32 + lc) * 128 + (byt ^ rsw));
        __builtin_amdgcn_s_setprio(1);
        accA = __builtin_amdgcn_mfma_f32_32x32x16_bf16(va, W.v, accA, 0, 0, 0);
        accB = __builtin_amdgcn_mfma_f32_32x32x16_bf16(vb, W.v, accB, 0, 0, 0);
        __builtin_amdgcn_s_setprio(0);
      }
    }
    __syncthreads();
  }

  // ---- epilogue: direct write, lane-local lsum (no merge) ----
  const float rl = 1.0f / lsum;
  const int h = bh & 15, b = bh >> 4;
  short* Ob = O + ((size_t)(b * S_ + q0w + lc)) * E_ + h * 64;
  #pragma unroll
  for (int gq = 0; gq < 4; ++gq) {
    short4v o0, o1;
    #pragma unroll
    for (int i = 0; i < 4; ++i) {
      o0[i] = f2b(accA[4 * gq + i] * rl);
      o1[i] = f2b(accB[4 * gq + i] * rl);
    }
    *(short4v*)(Ob + 8 * gq + 4 * hi) = o0;
    *(short4v*)(Ob + 32 + 8 * gq + 4 * hi) = o1;
  }
}

extern "C" void kernel_launch(void* const* d_in, const int* in_sizes, int n_in,
                              void* d_out, int out_size, void* d_ws, size_t ws_size,
                              hipStream_t stream)
{
  const float* x     = (const float*)d_in[0];
  const float* Wqkv  = (const float*)d_in[1];
  const float* bqkv  = (const float*)d_in[2];
  const float* Wproj = (const float*)d_in[3];
  const float* bproj = (const float*)d_in[4];
  float* out = (float*)d_out;

  char* ws = (char*)d_ws;
  short* xb     = (short*)(ws + (size_t)0);                 // 16 MB  [8192][1024]
  short* wqkvT  = (short*)(ws + (size_t)16 * 1024 * 1024);  //  6 MB  [3072][1024]
  short* wprojT = (short*)(ws + (size_t)22 * 1024 * 1024);  //  2 MB  [1024][1024]
  short* qb     = (short*)(ws + (size_t)24 * 1024 * 1024);  // 16 MB  [B][H][S][D] (scaled)
  short* kb     = (short*)(ws + (size_t)40 * 1024 * 1024);  // 16 MB  [B][H][S][D]
  short* vb     = (short*)(ws + (size_t)56 * 1024 * 1024);  // 16 MB  [B][H][D][S] (transposed)
  short* ob     = (short*)(ws + (size_t)72 * 1024 * 1024);  // 16 MB  [8192][1024]

  conv_kernel<<<4096, 256, 0, stream>>>(x, xb);
  trans_kernel<<<dim3(N1_ / 32, E_ / 32), 256, 0, stream>>>(Wqkv, wqkvT, E_, N1_);
  trans_kernel<<<dim3(E_ / 32, E_ / 32), 256, 0, stream>>>(Wproj, wprojT, E_, E_);
  gemm_kernel<true><<<dim3(N1_ / 128, M_ / 128), 256, 0, stream>>>(
      xb, wqkvT, bqkv, qb, kb, vb, nullptr, E_, N1_);
  attn_kernel<<<(S_ / 128) * (B_ * H_), 256, 0, stream>>>(qb, kb, vb, ob);
  gemm_kernel<false><<<dim3(E_ / 128, M_ / 128), 256, 0, stream>>>(
      ob, wprojT, bproj, nullptr, nullptr, nullptr, out, E_, E_);
}

// Round 11
// 161.098 us; speedup vs baseline: 1.5141x; 1.0192x over previous
//
#include <hip/hip_runtime.h>
#include <hip/hip_bf16.h>
#include <stdint.h>

#define B_ 4
#define S_ 2048
#define E_ 1024
#define H_ 16
#define D_ 64
#define M_ 8192     // B*S
#define N1_ 3072    // 3*E
#define QSCALE 0.18033688011112042f   // 0.125 * log2(e)

typedef __attribute__((ext_vector_type(8))) short bf16x8;
typedef __attribute__((ext_vector_type(4))) float f32x4;
typedef __attribute__((ext_vector_type(16))) float f32x16;
typedef __attribute__((ext_vector_type(4))) short short4v;

__device__ __forceinline__ short f2b(float f) {
  union { float f; unsigned u; } c; c.f = f;
  unsigned u = c.u + 0x7fffu + ((c.u >> 16) & 1u);
  return (short)(u >> 16);
}

__device__ __forceinline__ float fexp2(float x) {
#if __has_builtin(__builtin_amdgcn_exp2f)
  return __builtin_amdgcn_exp2f(x);
#else
  return exp2f(x);
#endif
}

__device__ __forceinline__ unsigned cvtpk(float lo, float hi2) {
  unsigned r;
  asm("v_cvt_pk_bf16_f32 %0, %1, %2" : "=v"(r) : "v"(lo), "v"(hi2));
  return r;
}

__device__ __forceinline__ void gload16(const void* g, void* l) {
  __builtin_amdgcn_global_load_lds((const __attribute__((address_space(1))) void*)g,
                                   (__attribute__((address_space(3))) void*)l, 16, 0, 0);
}

// ---- x (f32) -> bf16, 8 elems/thread ----
__global__ void conv_kernel(const float* __restrict__ in, short* __restrict__ out) {
  int idx = blockIdx.x * 256 + threadIdx.x;
  const float4* p = (const float4*)in;
  float4 a = p[(size_t)idx * 2];
  float4 b = p[(size_t)idx * 2 + 1];
  bf16x8 v;
  v[0] = f2b(a.x); v[1] = f2b(a.y); v[2] = f2b(a.z); v[3] = f2b(a.w);
  v[4] = f2b(b.x); v[5] = f2b(b.y); v[6] = f2b(b.z); v[7] = f2b(b.w);
  *(bf16x8*)(out + (size_t)idx * 8) = v;
}

// ---- fused transpose: Wqkv [E][3E] -> [3E][E] and Wproj [E][E] -> [E][E] ----
__global__ void trans_kernel(const float* __restrict__ inQ, short* __restrict__ outQ,
                             const float* __restrict__ inP, short* __restrict__ outP) {
  __shared__ float tile[32][33];
  const bool isP = blockIdx.x >= (N1_ / 32) * (E_ / 32);
  const int lin  = isP ? blockIdx.x - (N1_ / 32) * (E_ / 32) : blockIdx.x;
  const int NX   = isP ? (E_ / 32) : (N1_ / 32);
  const int N    = isP ? E_ : N1_;
  const float* in = isP ? inP : inQ;
  short* out      = isP ? outP : outQ;
  const int n0 = (lin % NX) * 32, k0 = (lin / NX) * 32;
  const int tx = threadIdx.x & 31, ty = threadIdx.x >> 5;
  #pragma unroll
  for (int i = 0; i < 4; ++i)
    tile[ty + i * 8][tx] = in[(size_t)(k0 + ty + i * 8) * N + n0 + tx];
  __syncthreads();
  #pragma unroll
  for (int i = 0; i < 4; ++i)
    out[(size_t)(n0 + ty + i * 8) * E_ + k0 + tx] = f2b(tile[tx][ty + i * 8]);
}

// ---- C[M][N] = A[M][K] * Bt[N][K]^T + bias ; bf16 MFMA, 128x128 tile, BK=64
//      (round-4 m97 structure: 32 KB LDS, multi-block implicit overlap) ----
template<bool SCATTER>
__global__ __launch_bounds__(256)
void gemm_kernel(const short* __restrict__ A, const short* __restrict__ Bt,
                 const float* __restrict__ bias,
                 short* __restrict__ oQ, short* __restrict__ oK, short* __restrict__ oV,
                 float* __restrict__ oC, int Kdim, int Ndim)
{
  __shared__ short Asub[128 * 64];
  __shared__ short Bsub[128 * 64];
  const int tid = threadIdx.x;
  const int l = tid & 63, w = tid >> 6;
  const int wr = w >> 1, wc = w & 1;
  const int lr = l & 15, lg = l >> 4;

  // T1: bijective XCD swizzle (nwg % 8 == 0 for both launches)
  const int nwg = gridDim.x * gridDim.y;
  const int lin = blockIdx.y * gridDim.x + blockIdx.x;
  const int lin2 = (lin & 7) * (nwg >> 3) + (lin >> 3);
  const int m0 = (lin2 / gridDim.x) * 128, n0 = (lin2 % gridDim.x) * 128;

  const int srow = w * 8 + (l >> 3);
  const int scol = ((l & 7) ^ (l >> 3)) << 3;   // pre-swizzled source col (elems)

  f32x4 acc[4][4] = {};

  for (int k0 = 0; k0 < Kdim; k0 += 64) {
    __syncthreads();
    #pragma unroll
    for (int i = 0; i < 4; ++i) {
      gload16(A  + (size_t)(m0 + i * 32 + srow) * Kdim + k0 + scol,
              (char*)Asub + (i * 32 + w * 8) * 128);
      gload16(Bt + (size_t)(n0 + i * 32 + srow) * Kdim + k0 + scol,
              (char*)Bsub + (i * 32 + w * 8) * 128);
    }
    __syncthreads();
    #pragma unroll
    for (int kk = 0; kk < 64; kk += 32) {
      bf16x8 af[4], bfr[4];
      const int ce2 = (kk + lg * 8) << 1;
      #pragma unroll
      for (int mi = 0; mi < 4; ++mi) {
        int rr = wr * 64 + mi * 16 + lr;
        af[mi] = *(const bf16x8*)((const char*)Asub + rr * 128 + (ce2 ^ ((rr & 7) << 4)));
      }
      #pragma unroll
      for (int ni = 0; ni < 4; ++ni) {
        int rr = wc * 64 + ni * 16 + lr;
        bfr[ni] = *(const bf16x8*)((const char*)Bsub + rr * 128 + (ce2 ^ ((rr & 7) << 4)));
      }
      __builtin_amdgcn_s_setprio(1);
      #pragma unroll
      for (int mi = 0; mi < 4; ++mi)
        #pragma unroll
        for (int ni = 0; ni < 4; ++ni)
          acc[mi][ni] = __builtin_amdgcn_mfma_f32_16x16x32_bf16(af[mi], bfr[ni], acc[mi][ni], 0, 0, 0);
      __builtin_amdgcn_s_setprio(0);
    }
  }

  #pragma unroll
  for (int mi = 0; mi < 4; ++mi) {
    #pragma unroll
    for (int ni = 0; ni < 4; ++ni) {
      const int row0 = m0 + wr * 64 + mi * 16 + lg * 4;
      const int col  = n0 + wc * 64 + ni * 16 + lr;
      const float bv = bias[col];
      if constexpr (SCATTER) {
        const int which = col >> 10;
        const int e = col & 1023;
        const int h = e >> 6, d = e & 63;
        const int b = row0 >> 11, s = row0 & 2047;
        if (which == 2) {
          short4v pv;
          #pragma unroll
          for (int r = 0; r < 4; ++r) pv[r] = f2b(acc[mi][ni][r] + bv);
          *(short4v*)(oV + ((size_t)((b * H_ + h) * D_ + d)) * S_ + s) = pv;
        } else {
          short* dst = which ? oK : oQ;
          const float sc = which ? 1.0f : QSCALE;
          #pragma unroll
          for (int r = 0; r < 4; ++r)
            dst[((size_t)((b * H_ + h) * S_ + s + r)) * D_ + d] = f2b((acc[mi][ni][r] + bv) * sc);
        }
      } else {
        #pragma unroll
        for (int r = 0; r < 4; ++r)
          oC[(size_t)(row0 + r) * Ndim + col] = acc[mi][ni][r] + bv;
      }
    }
  }
}

// ---- causal flash attention: 4 waves x 32 q-rows, NO KV split, 32 KB LDS
//      (4 blocks/CU), double-buffered K/V via global_load_lds, no-max softmax.
//      qt group map balances per-CU residency sets {g,g+4,g+8,g+12} to equal
//      work (sum 30) while dispatching heaviest blocks first. ----
__global__ __launch_bounds__(256, 4)
void attn_kernel(const short* __restrict__ Q, const short* __restrict__ K,
                 const short* __restrict__ vT, short* __restrict__ O)
{
  __shared__ short Kl[2][64 * 64];   // [par][key][d], rows XOR-swizzled
  __shared__ short Vl[2][64 * 64];   // [par][d][key], rows XOR-swizzled

  // balanced qt map: groups 0..15 -> {15,14,13,12, 8,9,10,11, 7,6,5,4, 0,1,2,3}
  const int g_ = blockIdx.x >> 6;
  const int sub = g_ & 3, quad = g_ >> 2;
  const int qt = (quad == 0) ? (15 - sub)
               : (quad == 1) ? (8 + sub)
               : (quad == 2) ? (7 - sub)
                             : sub;
  const int bh = blockIdx.x & 63;
  const int tid = threadIdx.x, l = tid & 63, w = tid >> 6;   // w = q-subtile 0..3
  const int lc = l & 31, hi = l >> 5;
  const int sl8 = l >> 3;
  const int scol = 8 * ((l & 7) ^ sl8);          // pre-swizzled source col (elems)

  const short* Qb = Q  + (size_t)bh * (S_ * D_);
  const short* Kb = K  + (size_t)bh * (S_ * D_);
  const short* Vg = vT + (size_t)bh * (S_ * D_);

  const int q0w = qt * 128 + w * 32;
  const int ktL = (q0w + 31) >> 6;       // last KV tile this q-subtile needs
  const int NTB = 2 * qt + 2;            // tiles the block stages

  bf16x8 qr[4];
  #pragma unroll
  for (int ds = 0; ds < 4; ++ds)
    qr[ds] = *(const bf16x8*)(Qb + (size_t)(q0w + lc) * D_ + ds * 16 + hi * 8);

  f32x16 accA{}, accB{};          // O^T accum: rows=d (dtile 0/1), col=q=lc
  float lsum = 0.f;
  const int rsw = (lc & 7) << 4;

  // each wave stages 16 K-rows and 16 V-rows per tile (2 gload16 each)
  auto stage = [&](int buf, int kt2) {
    short* kl = &Kl[buf][(w * 16) * 64];
    short* vl = &Vl[buf][(w * 16) * 64];
    const size_t kr = (size_t)(kt2 * 64 + w * 16 + sl8);
    gload16(Kb + kr * 64 + scol, kl);
    gload16(Kb + (kr + 8) * 64 + scol, kl + 8 * 64);
    const size_t vr = (size_t)(w * 16 + sl8);
    gload16(Vg + vr * S_ + kt2 * 64 + scol, vl);
    gload16(Vg + (vr + 8) * S_ + kt2 * 64 + scol, vl + 8 * 64);
  };

  stage(0, 0);
  __syncthreads();

  for (int kt = 0; kt < NTB; ++kt) {
    const int cur = kt & 1;
    if (kt + 1 < NTB) stage(cur ^ 1, kt + 1);

    if (kt <= ktL) {
      const char* Kc = (const char*)Kl[cur];
      const char* Vc = (const char*)Vl[cur];
      // ---- S^T = K * Q^T ----
      f32x16 s0{}, s1{};
      __builtin_amdgcn_s_setprio(1);
      #pragma unroll
      for (int ds = 0; ds < 4; ++ds) {
        const int byt = ds * 32 + hi * 16;
        bf16x8 a0 = *(const bf16x8*)(Kc + lc * 128 + (byt ^ rsw));
        bf16x8 a1 = *(const bf16x8*)(Kc + (32 + lc) * 128 + (byt ^ rsw));
        s0 = __builtin_amdgcn_mfma_f32_32x32x16_bf16(a0, qr[ds], s0, 0, 0, 0);
        s1 = __builtin_amdgcn_mfma_f32_32x32x16_bf16(a1, qr[ds], s1, 0, 0, 0);
      }
      __builtin_amdgcn_s_setprio(0);
      float p[32];
      #pragma unroll
      for (int r = 0; r < 16; ++r) { p[r] = s0[r]; p[16 + r] = s1[r]; }
      if (kt == ktL) {           // diagonal tile: mask key > q
        const int qq = q0w + lc - kt * 64;
        #pragma unroll
        for (int r = 0; r < 16; ++r) {
          const int k0 = (r & 3) + 8 * (r >> 2) + 4 * hi;
          if (k0 > qq)      p[r]      = -1e30f;
          if (k0 + 32 > qq) p[16 + r] = -1e30f;
        }
      }
      // ---- no-max softmax: p = exp2(s) raw (s already in log2 units) ----
      float rs0 = 0.f, rs1 = 0.f, rs2 = 0.f, rs3 = 0.f;
      #pragma unroll
      for (int r = 0; r < 8; ++r) {
        p[r]      = fexp2(p[r]);      rs0 += p[r];
        p[8 + r]  = fexp2(p[8 + r]);  rs1 += p[8 + r];
        p[16 + r] = fexp2(p[16 + r]); rs2 += p[16 + r];
        p[24 + r] = fexp2(p[24 + r]); rs3 += p[24 + r];
      }
      float rs = (rs0 + rs1) + (rs2 + rs3);
      rs += __shfl_xor(rs, 32);
      lsum += rs;
      // ---- O^T += V^T * P^T ----
      #pragma unroll
      for (int ks = 0; ks < 4; ++ks) {
        const int b8 = ks * 8;
        const unsigned A0 = cvtpk(p[b8 + 0], p[b8 + 1]);
        const unsigned A1 = cvtpk(p[b8 + 2], p[b8 + 3]);
        const unsigned B0 = cvtpk(p[b8 + 4], p[b8 + 5]);
        const unsigned B1 = cvtpk(p[b8 + 6], p[b8 + 7]);
        const unsigned u0 = __shfl_xor(hi ? A0 : B0, 32);
        const unsigned u1 = __shfl_xor(hi ? A1 : B1, 32);
        union { unsigned u[4]; bf16x8 v; } W;
        W.u[0] = hi ? u0 : A0;
        W.u[1] = hi ? u1 : A1;
        W.u[2] = hi ? B0 : u0;
        W.u[3] = hi ? B1 : u1;
        const int byt = ks * 32 + hi * 16;
        bf16x8 va = *(const bf16x8*)(Vc + lc * 128 + (byt ^ rsw));
        bf16x8 vb = *(const bf16x8*)(Vc + (32 + lc) * 128 + (byt ^ rsw));
        __builtin_amdgcn_s_setprio(1);
        accA = __builtin_amdgcn_mfma_f32_32x32x16_bf16(va, W.v, accA, 0, 0, 0);
        accB = __builtin_amdgcn_mfma_f32_32x32x16_bf16(vb, W.v, accB, 0, 0, 0);
        __builtin_amdgcn_s_setprio(0);
      }
    }
    __syncthreads();
  }

  // ---- epilogue: direct write, lane-local lsum (no merge) ----
  const float rl = 1.0f / lsum;
  const int h = bh & 15, b = bh >> 4;
  short* Ob = O + ((size_t)(b * S_ + q0w + lc)) * E_ + h * 64;
  #pragma unroll
  for (int gq = 0; gq < 4; ++gq) {
    short4v o0, o1;
    #pragma unroll
    for (int i = 0; i < 4; ++i) {
      o0[i] = f2b(accA[4 * gq + i] * rl);
      o1[i] = f2b(accB[4 * gq + i] * rl);
    }
    *(short4v*)(Ob + 8 * gq + 4 * hi) = o0;
    *(short4v*)(Ob + 32 + 8 * gq + 4 * hi) = o1;
  }
}

extern "C" void kernel_launch(void* const* d_in, const int* in_sizes, int n_in,
                              void* d_out, int out_size, void* d_ws, size_t ws_size,
                              hipStream_t stream)
{
  const float* x     = (const float*)d_in[0];
  const float* Wqkv  = (const float*)d_in[1];
  const float* bqkv  = (const float*)d_in[2];
  const float* Wproj = (const float*)d_in[3];
  const float* bproj = (const float*)d_in[4];
  float* out = (float*)d_out;

  char* ws = (char*)d_ws;
  short* xb     = (short*)(ws + (size_t)0);                 // 16 MB  [8192][1024]
  short* wqkvT  = (short*)(ws + (size_t)16 * 1024 * 1024);  //  6 MB  [3072][1024]
  short* wprojT = (short*)(ws + (size_t)22 * 1024 * 1024);  //  2 MB  [1024][1024]
  short* qb     = (short*)(ws + (size_t)24 * 1024 * 1024);  // 16 MB  [B][H][S][D] (scaled)
  short* kb     = (short*)(ws + (size_t)40 * 1024 * 1024);  // 16 MB  [B][H][S][D]
  short* vb     = (short*)(ws + (size_t)56 * 1024 * 1024);  // 16 MB  [B][H][D][S] (transposed)
  short* ob     = (short*)(ws + (size_t)72 * 1024 * 1024);  // 16 MB  [8192][1024]

  conv_kernel<<<4096, 256, 0, stream>>>(x, xb);
  trans_kernel<<<(N1_ / 32) * (E_ / 32) + (E_ / 32) * (E_ / 32), 256, 0, stream>>>(
      Wqkv, wqkvT, Wproj, wprojT);
  gemm_kernel<true><<<dim3(N1_ / 128, M_ / 128), 256, 0, stream>>>(
      xb, wqkvT, bqkv, qb, kb, vb, nullptr, E_, N1_);
  attn_kernel<<<(S_ / 128) * (B_ * H_), 256, 0, stream>>>(qb, kb, vb, ob);
  gemm_kernel<false><<<dim3(E_ / 128, M_ / 128), 256, 0, stream>>>(
      ob, wprojT, bproj, nullptr, nullptr, nullptr, out, E_, E_);
}

// Round 12
// 160.893 us; speedup vs baseline: 1.5161x; 1.0013x over previous
//
#include <hip/hip_runtime.h>
#include <hip/hip_bf16.h>
#include <stdint.h>

#define B_ 4
#define S_ 2048
#define E_ 1024
#define H_ 16
#define D_ 64
#define M_ 8192     // B*S
#define N1_ 3072    // 3*E
#define QSCALE 0.18033688011112042f   // 0.125 * log2(e)

typedef __attribute__((ext_vector_type(8))) short bf16x8;
typedef __attribute__((ext_vector_type(4))) float f32x4;
typedef __attribute__((ext_vector_type(16))) float f32x16;
typedef __attribute__((ext_vector_type(4))) short short4v;

__device__ __forceinline__ short f2b(float f) {
  union { float f; unsigned u; } c; c.f = f;
  unsigned u = c.u + 0x7fffu + ((c.u >> 16) & 1u);
  return (short)(u >> 16);
}

__device__ __forceinline__ float fexp2(float x) {
#if __has_builtin(__builtin_amdgcn_exp2f)
  return __builtin_amdgcn_exp2f(x);
#else
  return exp2f(x);
#endif
}

__device__ __forceinline__ unsigned cvtpk(float lo, float hi2) {
  unsigned r;
  asm("v_cvt_pk_bf16_f32 %0, %1, %2" : "=v"(r) : "v"(lo), "v"(hi2));
  return r;
}

__device__ __forceinline__ void gload16(const void* g, void* l) {
  __builtin_amdgcn_global_load_lds((const __attribute__((address_space(1))) void*)g,
                                   (__attribute__((address_space(3))) void*)l, 16, 0, 0);
}

// ---- fused prep: x f32->bf16 (blocks [0,4096)), Wqkv transpose ([4096,7168)),
//      Wproj transpose (rest). One launch instead of three. ----
#define NCONV 4096
#define NTQ   ((N1_ / 32) * (E_ / 32))
#define NTP   ((E_ / 32) * (E_ / 32))
__global__ __launch_bounds__(256)
void prep_kernel(const float* __restrict__ x, short* __restrict__ xb,
                 const float* __restrict__ Wqkv, short* __restrict__ wqkvT,
                 const float* __restrict__ Wproj, short* __restrict__ wprojT) {
  __shared__ float tile[32][33];
  const int bid = blockIdx.x, tid = threadIdx.x;
  if (bid < NCONV) {
    int idx = bid * 256 + tid;
    const float4* p = (const float4*)x;
    float4 a = p[(size_t)idx * 2];
    float4 b = p[(size_t)idx * 2 + 1];
    bf16x8 v;
    v[0] = f2b(a.x); v[1] = f2b(a.y); v[2] = f2b(a.z); v[3] = f2b(a.w);
    v[4] = f2b(b.x); v[5] = f2b(b.y); v[6] = f2b(b.z); v[7] = f2b(b.w);
    *(bf16x8*)(xb + (size_t)idx * 8) = v;
    return;
  }
  const bool isP = bid >= NCONV + NTQ;
  const int lin  = isP ? bid - NCONV - NTQ : bid - NCONV;
  const int NX   = isP ? (E_ / 32) : (N1_ / 32);
  const int N    = isP ? E_ : N1_;
  const float* in = isP ? Wproj : Wqkv;
  short* out      = isP ? wprojT : wqkvT;
  const int n0 = (lin % NX) * 32, k0 = (lin / NX) * 32;
  const int tx = tid & 31, ty = tid >> 5;
  #pragma unroll
  for (int i = 0; i < 4; ++i)
    tile[ty + i * 8][tx] = in[(size_t)(k0 + ty + i * 8) * N + n0 + tx];
  __syncthreads();
  #pragma unroll
  for (int i = 0; i < 4; ++i)
    out[(size_t)(n0 + ty + i * 8) * E_ + k0 + tx] = f2b(tile[tx][ty + i * 8]);
}

// ---- C[M][N] = A[M][K] * Bt[N][K]^T + bias ; bf16 MFMA, 128x128 tile, BK=64
//      (m97 structure: 32 KB LDS, multi-block implicit overlap) ----
template<bool SCATTER>
__global__ __launch_bounds__(256)
void gemm_kernel(const short* __restrict__ A, const short* __restrict__ Bt,
                 const float* __restrict__ bias,
                 short* __restrict__ oQ, short* __restrict__ oK, short* __restrict__ oV,
                 float* __restrict__ oC, int Kdim, int Ndim)
{
  __shared__ short Asub[128 * 64];
  __shared__ short Bsub[128 * 64];
  const int tid = threadIdx.x;
  const int l = tid & 63, w = tid >> 6;
  const int wr = w >> 1, wc = w & 1;
  const int lr = l & 15, lg = l >> 4;

  // T1: bijective XCD swizzle (nwg % 8 == 0 for both launches)
  const int nwg = gridDim.x * gridDim.y;
  const int lin = blockIdx.y * gridDim.x + blockIdx.x;
  const int lin2 = (lin & 7) * (nwg >> 3) + (lin >> 3);
  const int m0 = (lin2 / gridDim.x) * 128, n0 = (lin2 % gridDim.x) * 128;

  const int srow = w * 8 + (l >> 3);
  const int scol = ((l & 7) ^ (l >> 3)) << 3;   // pre-swizzled source col (elems)

  f32x4 acc[4][4] = {};

  for (int k0 = 0; k0 < Kdim; k0 += 64) {
    __syncthreads();
    #pragma unroll
    for (int i = 0; i < 4; ++i) {
      gload16(A  + (size_t)(m0 + i * 32 + srow) * Kdim + k0 + scol,
              (char*)Asub + (i * 32 + w * 8) * 128);
      gload16(Bt + (size_t)(n0 + i * 32 + srow) * Kdim + k0 + scol,
              (char*)Bsub + (i * 32 + w * 8) * 128);
    }
    __syncthreads();
    #pragma unroll
    for (int kk = 0; kk < 64; kk += 32) {
      bf16x8 af[4], bfr[4];
      const int ce2 = (kk + lg * 8) << 1;
      #pragma unroll
      for (int mi = 0; mi < 4; ++mi) {
        int rr = wr * 64 + mi * 16 + lr;
        af[mi] = *(const bf16x8*)((const char*)Asub + rr * 128 + (ce2 ^ ((rr & 7) << 4)));
      }
      #pragma unroll
      for (int ni = 0; ni < 4; ++ni) {
        int rr = wc * 64 + ni * 16 + lr;
        bfr[ni] = *(const bf16x8*)((const char*)Bsub + rr * 128 + (ce2 ^ ((rr & 7) << 4)));
      }
      __builtin_amdgcn_s_setprio(1);
      #pragma unroll
      for (int mi = 0; mi < 4; ++mi)
        #pragma unroll
        for (int ni = 0; ni < 4; ++ni)
          acc[mi][ni] = __builtin_amdgcn_mfma_f32_16x16x32_bf16(af[mi], bfr[ni], acc[mi][ni], 0, 0, 0);
      __builtin_amdgcn_s_setprio(0);
    }
  }

  #pragma unroll
  for (int mi = 0; mi < 4; ++mi) {
    #pragma unroll
    for (int ni = 0; ni < 4; ++ni) {
      const int row0 = m0 + wr * 64 + mi * 16 + lg * 4;
      const int col  = n0 + wc * 64 + ni * 16 + lr;
      const float bv = bias[col];
      if constexpr (SCATTER) {
        const int which = col >> 10;
        const int e = col & 1023;
        const int h = e >> 6, d = e & 63;
        const int b = row0 >> 11, s = row0 & 2047;
        if (which == 2) {
          short4v pv;
          #pragma unroll
          for (int r = 0; r < 4; ++r) pv[r] = f2b(acc[mi][ni][r] + bv);
          *(short4v*)(oV + ((size_t)((b * H_ + h) * D_ + d)) * S_ + s) = pv;
        } else {
          short* dst = which ? oK : oQ;
          const float sc = which ? 1.0f : QSCALE;
          #pragma unroll
          for (int r = 0; r < 4; ++r)
            dst[((size_t)((b * H_ + h) * S_ + s + r)) * D_ + d] = f2b((acc[mi][ni][r] + bv) * sc);
        }
      } else {
        #pragma unroll
        for (int r = 0; r < 4; ++r)
          oC[(size_t)(row0 + r) * Ndim + col] = acc[mi][ni][r] + bv;
      }
    }
  }
}

// ---- causal flash attention: 4 waves x 32 q-rows, 32 KB LDS (4 blocks/CU),
//      double-buffered K/V via global_load_lds, no-max softmax, balanced qt map.
//      Diagonal tile: even waves (qq=lc<32) skip the fully-masked hi 32 keys
//      (s1 QK chain, exp2, PV ks=2,3); odd waves skip the no-op s0 mask. ----
__global__ __launch_bounds__(256, 4)
void attn_kernel(const short* __restrict__ Q, const short* __restrict__ K,
                 const short* __restrict__ vT, short* __restrict__ O)
{
  __shared__ short Kl[2][64 * 64];   // [par][key][d], rows XOR-swizzled
  __shared__ short Vl[2][64 * 64];   // [par][d][key], rows XOR-swizzled

  // balanced qt map: groups 0..15 -> {15,14,13,12, 8,9,10,11, 7,6,5,4, 0,1,2,3}
  const int g_ = blockIdx.x >> 6;
  const int sub = g_ & 3, quad = g_ >> 2;
  const int qt = (quad == 0) ? (15 - sub)
               : (quad == 1) ? (8 + sub)
               : (quad == 2) ? (7 - sub)
                             : sub;
  const int bh = blockIdx.x & 63;
  const int tid = threadIdx.x, l = tid & 63, w = tid >> 6;   // w = q-subtile 0..3
  const int lc = l & 31, hi = l >> 5;
  const int sl8 = l >> 3;
  const int scol = 8 * ((l & 7) ^ sl8);          // pre-swizzled source col (elems)

  const short* Qb = Q  + (size_t)bh * (S_ * D_);
  const short* Kb = K  + (size_t)bh * (S_ * D_);
  const short* Vg = vT + (size_t)bh * (S_ * D_);

  const int q0w = qt * 128 + w * 32;
  const int ktL = (q0w + 31) >> 6;       // last KV tile this q-subtile needs
  const int NTB = 2 * qt + 2;            // tiles the block stages
  const bool evenW = ((w & 1) == 0);     // diagonal tile => qq = lc in [0,31]

  bf16x8 qr[4];
  #pragma unroll
  for (int ds = 0; ds < 4; ++ds)
    qr[ds] = *(const bf16x8*)(Qb + (size_t)(q0w + lc) * D_ + ds * 16 + hi * 8);

  f32x16 accA{}, accB{};          // O^T accum: rows=d (dtile 0/1), col=q=lc
  float lsum = 0.f;
  const int rsw = (lc & 7) << 4;

  // each wave stages 16 K-rows and 16 V-rows per tile (2 gload16 each)
  auto stage = [&](int buf, int kt2) {
    short* kl = &Kl[buf][(w * 16) * 64];
    short* vl = &Vl[buf][(w * 16) * 64];
    const size_t kr = (size_t)(kt2 * 64 + w * 16 + sl8);
    gload16(Kb + kr * 64 + scol, kl);
    gload16(Kb + (kr + 8) * 64 + scol, kl + 8 * 64);
    const size_t vr = (size_t)(w * 16 + sl8);
    gload16(Vg + vr * S_ + kt2 * 64 + scol, vl);
    gload16(Vg + (vr + 8) * S_ + kt2 * 64 + scol, vl + 8 * 64);
  };

  stage(0, 0);
  __syncthreads();

  for (int kt = 0; kt < NTB; ++kt) {
    const int cur = kt & 1;
    if (kt + 1 < NTB) stage(cur ^ 1, kt + 1);

    if (kt <= ktL) {
      const char* Kc = (const char*)Kl[cur];
      const char* Vc = (const char*)Vl[cur];
      const bool diag = (kt == ktL);
      const bool doHi = !(diag && evenW);   // hi 32 keys fully masked?
      // ---- S^T = K * Q^T ----
      f32x16 s0{}, s1{};
      __builtin_amdgcn_s_setprio(1);
      #pragma unroll
      for (int ds = 0; ds < 4; ++ds) {
        const int byt = ds * 32 + hi * 16;
        bf16x8 a0 = *(const bf16x8*)(Kc + lc * 128 + (byt ^ rsw));
        s0 = __builtin_amdgcn_mfma_f32_32x32x16_bf16(a0, qr[ds], s0, 0, 0, 0);
      }
      if (doHi) {
        #pragma unroll
        for (int ds = 0; ds < 4; ++ds) {
          const int byt = ds * 32 + hi * 16;
          bf16x8 a1 = *(const bf16x8*)(Kc + (32 + lc) * 128 + (byt ^ rsw));
          s1 = __builtin_amdgcn_mfma_f32_32x32x16_bf16(a1, qr[ds], s1, 0, 0, 0);
        }
      }
      __builtin_amdgcn_s_setprio(0);
      float p[32];
      #pragma unroll
      for (int r = 0; r < 16; ++r) { p[r] = s0[r]; p[16 + r] = s1[r]; }
      if (diag) {
        const int qq = q0w + lc - kt * 64;   // even waves: lc; odd: 32+lc
        if (evenW) {
          #pragma unroll
          for (int r = 0; r < 16; ++r) {
            const int k0 = (r & 3) + 8 * (r >> 2) + 4 * hi;
            if (k0 > qq) p[r] = -1e30f;      // s1 skipped entirely
          }
        } else {
          #pragma unroll
          for (int r = 0; r < 16; ++r) {     // s0 provably unmasked
            const int k0 = (r & 3) + 8 * (r >> 2) + 4 * hi;
            if (k0 + 32 > qq) p[16 + r] = -1e30f;
          }
        }
      }
      // ---- no-max softmax: p = exp2(s) raw (s already in log2 units) ----
      float rs0 = 0.f, rs1 = 0.f, rs2 = 0.f, rs3 = 0.f;
      #pragma unroll
      for (int r = 0; r < 8; ++r) {
        p[r]     = fexp2(p[r]);     rs0 += p[r];
        p[8 + r] = fexp2(p[8 + r]); rs1 += p[8 + r];
      }
      if (doHi) {
        #pragma unroll
        for (int r = 0; r < 8; ++r) {
          p[16 + r] = fexp2(p[16 + r]); rs2 += p[16 + r];
          p[24 + r] = fexp2(p[24 + r]); rs3 += p[24 + r];
        }
      }
      float rs = (rs0 + rs1) + (rs2 + rs3);
      rs += __shfl_xor(rs, 32);
      lsum += rs;
      // ---- O^T += V^T * P^T (ks=2,3 consume p[16..31]: skip when !doHi) ----
      #pragma unroll
      for (int ks = 0; ks < 4; ++ks) {
        if (ks >= 2 && !doHi) continue;
        const int b8 = ks * 8;
        const unsigned A0 = cvtpk(p[b8 + 0], p[b8 + 1]);
        const unsigned A1 = cvtpk(p[b8 + 2], p[b8 + 3]);
        const unsigned B0 = cvtpk(p[b8 + 4], p[b8 + 5]);
        const unsigned B1 = cvtpk(p[b8 + 6], p[b8 + 7]);
        const unsigned u0 = __shfl_xor(hi ? A0 : B0, 32);
        const unsigned u1 = __shfl_xor(hi ? A1 : B1, 32);
        union { unsigned u[4]; bf16x8 v; } W;
        W.u[0] = hi ? u0 : A0;
        W.u[1] = hi ? u1 : A1;
        W.u[2] = hi ? B0 : u0;
        W.u[3] = hi ? B1 : u1;
        const int byt = ks * 32 + hi * 16;
        bf16x8 va = *(const bf16x8*)(Vc + lc * 128 + (byt ^ rsw));
        bf16x8 vb = *(const bf16x8*)(Vc + (32 + lc) * 128 + (byt ^ rsw));
        __builtin_amdgcn_s_setprio(1);
        accA = __builtin_amdgcn_mfma_f32_32x32x16_bf16(va, W.v, accA, 0, 0, 0);
        accB = __builtin_amdgcn_mfma_f32_32x32x16_bf16(vb, W.v, accB, 0, 0, 0);
        __builtin_amdgcn_s_setprio(0);
      }
    }
    __syncthreads();
  }

  // ---- epilogue: direct write, lane-local lsum (no merge) ----
  const float rl = 1.0f / lsum;
  const int h = bh & 15, b = bh >> 4;
  short* Ob = O + ((size_t)(b * S_ + q0w + lc)) * E_ + h * 64;
  #pragma unroll
  for (int gq = 0; gq < 4; ++gq) {
    short4v o0, o1;
    #pragma unroll
    for (int i = 0; i < 4; ++i) {
      o0[i] = f2b(accA[4 * gq + i] * rl);
      o1[i] = f2b(accB[4 * gq + i] * rl);
    }
    *(short4v*)(Ob + 8 * gq + 4 * hi) = o0;
    *(short4v*)(Ob + 32 + 8 * gq + 4 * hi) = o1;
  }
}

extern "C" void kernel_launch(void* const* d_in, const int* in_sizes, int n_in,
                              void* d_out, int out_size, void* d_ws, size_t ws_size,
                              hipStream_t stream)
{
  const float* x     = (const float*)d_in[0];
  const float* Wqkv  = (const float*)d_in[1];
  const float* bqkv  = (const float*)d_in[2];
  const float* Wproj = (const float*)d_in[3];
  const float* bproj = (const float*)d_in[4];
  float* out = (float*)d_out;

  char* ws = (char*)d_ws;
  short* xb     = (short*)(ws + (size_t)0);                 // 16 MB  [8192][1024]
  short* wqkvT  = (short*)(ws + (size_t)16 * 1024 * 1024);  //  6 MB  [3072][1024]
  short* wprojT = (short*)(ws + (size_t)22 * 1024 * 1024);  //  2 MB  [1024][1024]
  short* qb     = (short*)(ws + (size_t)24 * 1024 * 1024);  // 16 MB  [B][H][S][D] (scaled)
  short* kb     = (short*)(ws + (size_t)40 * 1024 * 1024);  // 16 MB  [B][H][S][D]
  short* vb     = (short*)(ws + (size_t)56 * 1024 * 1024);  // 16 MB  [B][H][D][S] (transposed)
  short* ob     = (short*)(ws + (size_t)72 * 1024 * 1024);  // 16 MB  [8192][1024]

  prep_kernel<<<NCONV + NTQ + NTP, 256, 0, stream>>>(x, xb, Wqkv, wqkvT, Wproj, wprojT);
  gemm_kernel<true><<<dim3(N1_ / 128, M_ / 128), 256, 0, stream>>>(
      xb, wqkvT, bqkv, qb, kb, vb, nullptr, E_, N1_);
  attn_kernel<<<(S_ / 128) * (B_ * H_), 256, 0, stream>>>(qb, kb, vb, ob);
  gemm_kernel<false><<<dim3(E_ / 128, M_ / 128), 256, 0, stream>>>(
      ob, wprojT, bproj, nullptr, nullptr, nullptr, out, E_, E_);
}